// Round 3
// baseline (515.078 us; speedup 1.0000x reference)
//
#include <hip/hip_runtime.h>

// GCN: 3x (GEMM -> CSR aggregate -> bias/relu -> BN-stats), BN folded into next GEMM,
// then segment mean-pool + linear head + softmax.
// Sizes fixed by problem: N=65536 nodes, E=1048576 edges, F=H=64, 64 graphs, 16 classes.
// CSR build: deg -> scan -> 2-level bucketed fill (avoids 64B-line write amplification
// of fully-random 4B scatter; round 2 showed k_fill at 72MB HBM write for 4MB payload).

__global__ void k_deg(const int* __restrict__ ei, int E, int* __restrict__ deg) {
    int e = blockIdx.x * blockDim.x + threadIdx.x;
    if (e < E) atomicAdd(&deg[ei[E + e]], 1);
}

__global__ void k_scan1(const int* __restrict__ deg, int* __restrict__ rowptr,
                        int* __restrict__ chunk) {
    __shared__ int s[256];
    int t = threadIdx.x, b = blockIdx.x;
    int v = deg[b * 256 + t];
    s[t] = v;
    __syncthreads();
    for (int o = 1; o < 256; o <<= 1) {
        int x = (t >= o) ? s[t - o] : 0;
        __syncthreads();
        s[t] += x;
        __syncthreads();
    }
    rowptr[b * 256 + t] = s[t] - v;  // local exclusive
    if (t == 255) chunk[b] = s[255];
}

__global__ void k_scan2(int* __restrict__ chunk) {
    __shared__ int s[256];
    int t = threadIdx.x;
    int v = chunk[t];
    s[t] = v;
    __syncthreads();
    for (int o = 1; o < 256; o <<= 1) {
        int x = (t >= o) ? s[t - o] : 0;
        __syncthreads();
        s[t] += x;
        __syncthreads();
    }
    chunk[t] = s[t] - v;  // exclusive
}

__global__ void k_scan3(int* __restrict__ rowptr, const int* __restrict__ chunk,
                        int* __restrict__ bcur, const int* __restrict__ deg,
                        float* __restrict__ dinv, int N, int E) {
    int n = blockIdx.x * 256 + threadIdx.x;
    int r = rowptr[n] + chunk[blockIdx.x];
    rowptr[n] = r;
    if ((n & 63) == 0) bcur[n >> 6] = r;   // bucket base = rowptr at 64-node boundary
    dinv[n] = rsqrtf((float)(deg[n] + 1));  // +1 self loop
    if (n == 0) rowptr[N] = E;
}

// pass 1: scatter edges into per-bucket segments (bucket = dst>>6, exact layout via rowptr).
// entry packs (src<<6)|dstlow; consecutive atomic slots per bucket -> dense line fill.
__global__ void k_bkt(const int* __restrict__ ei, int E, int* __restrict__ bcur,
                      int* __restrict__ buck) {
    int e = blockIdx.x * blockDim.x + threadIdx.x;
    if (e < E) {
        int s = ei[e], d = ei[E + e];
        int p = atomicAdd(&bcur[d >> 6], 1);
        buck[p] = (s << 6) | (d & 63);
    }
}

// pass 2: one block per bucket; within-bucket cursors in LDS; csr writes confined to the
// bucket's contiguous window (single CU -> fully dirty lines).
__global__ void k_place(const int* __restrict__ rowptr, const int* __restrict__ buck,
                        int* __restrict__ csr) {
    __shared__ int cur[64];
    int b = blockIdx.x, t = threadIdx.x;
    if (t < 64) cur[t] = rowptr[b * 64 + t];
    int beg = rowptr[b * 64];
    int end = rowptr[b * 64 + 64];
    __syncthreads();
    for (int i = beg + t; i < end; i += 256) {
        int v = buck[i];
        int d = v & 63;
        int s = v >> 6;
        int p = atomicAdd(&cur[d], 1);
        csr[p] = s;
    }
}

// Fold BN(prev layer) into W: Wf[f][j] = rstd[f]*W[f][j]; brow[j] = -sum_f mean[f]*rstd[f]*W[f][j]
__global__ void k_fold(const float* __restrict__ W, const float* __restrict__ mean,
                       const float* __restrict__ rstd, int has_stats,
                       float* __restrict__ Wf, float* __restrict__ brow) {
    __shared__ float sm[64], sr[64];
    int t = threadIdx.x;
    if (t < 64) {
        sm[t] = has_stats ? mean[t] : 0.0f;
        sr[t] = has_stats ? rstd[t] : 1.0f;
    }
    __syncthreads();
    for (int i = t; i < 4096; i += 256) {
        int f = i >> 6;
        Wf[i] = sr[f] * W[i];
    }
    if (t < 64) {
        float acc = 0.0f;
        for (int f = 0; f < 64; ++f) acc += sm[f] * sr[f] * W[f * 64 + t];
        brow[t] = -acc;
    }
}

// y[n][j] = dinv[n] * ( sum_f h[n][f]*Wf[f][j] + brow[j] )
// block 256 threads, 64 rows/block; thread = 4x4 output tile (rg=row group, cg=col group)
// hs padded to stride 65 floats: max 2-way LDS conflict (free)
__global__ void k_gemm(const float* __restrict__ h, const float* __restrict__ Wf,
                       const float* __restrict__ brow, const float* __restrict__ dinv,
                       float* __restrict__ y) {
    __shared__ float Ws[4096];        // [f][c] 64x64
    __shared__ float hs[64 * 65];     // [row][f], stride 65
    int t = threadIdx.x;
    int rowBase = blockIdx.x * 64;
#pragma unroll
    for (int k = 0; k < 4; ++k)
        ((float4*)Ws)[t + k * 256] = ((const float4*)Wf)[t + k * 256];
#pragma unroll
    for (int k = 0; k < 4; ++k) {
        int i = t + k * 256;              // 0..1023 float4s of the h block
        int row = i >> 4, c4 = i & 15;
        float4 v = ((const float4*)(h + (size_t)rowBase * 64))[i];
        float* dst = &hs[row * 65 + c4 * 4];
        dst[0] = v.x; dst[1] = v.y; dst[2] = v.z; dst[3] = v.w;
    }
    __syncthreads();
    int rg = t >> 4;   // 0..15, rows rg*4..rg*4+3
    int cg = t & 15;   // 0..15, cols cg*4..cg*4+3
    float4 a0, a1, a2, a3;
    {
        float bx = brow[cg * 4 + 0], by = brow[cg * 4 + 1];
        float bz = brow[cg * 4 + 2], bw = brow[cg * 4 + 3];
        a0 = {bx, by, bz, bw}; a1 = a0; a2 = a0; a3 = a0;
    }
    const float* h0 = &hs[(rg * 4 + 0) * 65];
    const float* h1 = &hs[(rg * 4 + 1) * 65];
    const float* h2 = &hs[(rg * 4 + 2) * 65];
    const float* h3 = &hs[(rg * 4 + 3) * 65];
#pragma unroll 4
    for (int f = 0; f < 64; ++f) {
        float4 wv = ((float4*)Ws)[f * 16 + cg];
        float v0 = h0[f], v1 = h1[f], v2 = h2[f], v3 = h3[f];
        a0.x += v0 * wv.x; a0.y += v0 * wv.y; a0.z += v0 * wv.z; a0.w += v0 * wv.w;
        a1.x += v1 * wv.x; a1.y += v1 * wv.y; a1.z += v1 * wv.z; a1.w += v1 * wv.w;
        a2.x += v2 * wv.x; a2.y += v2 * wv.y; a2.z += v2 * wv.z; a2.w += v2 * wv.w;
        a3.x += v3 * wv.x; a3.y += v3 * wv.y; a3.z += v3 * wv.z; a3.w += v3 * wv.w;
    }
    float d0 = dinv[rowBase + rg * 4 + 0];
    float d1 = dinv[rowBase + rg * 4 + 1];
    float d2 = dinv[rowBase + rg * 4 + 2];
    float d3 = dinv[rowBase + rg * 4 + 3];
    a0.x *= d0; a0.y *= d0; a0.z *= d0; a0.w *= d0;
    a1.x *= d1; a1.y *= d1; a1.z *= d1; a1.w *= d1;
    a2.x *= d2; a2.y *= d2; a2.z *= d2; a2.w *= d2;
    a3.x *= d3; a3.y *= d3; a3.z *= d3; a3.w *= d3;
    float4* y4 = (float4*)y;
    size_t ob = (size_t)(rowBase + rg * 4) * 16 + cg;
    y4[ob + 0]  = a0;
    y4[ob + 16] = a1;
    y4[ob + 32] = a2;
    y4[ob + 48] = a3;
}

// out[n] = relu?( dinv[n]*(y[n] + sum_{src in csr[n]} y[src]) + bias )
// 8-wide unrolled gather with clamped-index predication: 8 loads in flight per wave.
// also accumulates per-block BN partial sums (sum, sumsq) per feature.
template <int RELU>
__global__ void k_agg(const float* __restrict__ y, const int* __restrict__ rowptr,
                      const int* __restrict__ csr, const float* __restrict__ dinv,
                      const float* __restrict__ bias, float* __restrict__ hout,
                      float* __restrict__ partials, int N) {
    int t = threadIdx.x;
    int lane = t & 63;
    int wid = t >> 6;                       // 0..7
    int gwave = blockIdx.x * 8 + wid;       // 0..16383
    float b = bias[lane];
    float ps = 0.0f, pq = 0.0f;
    for (int n = gwave; n < N; n += 16384) {
        int beg = rowptr[n], end = rowptr[n + 1];
        float a0 = y[(size_t)n * 64 + lane];
        float a1 = 0.0f, a2 = 0.0f, a3 = 0.0f;
        float a4 = 0.0f, a5 = 0.0f, a6 = 0.0f, a7 = 0.0f;
        for (int k = beg; k < end; k += 8) {
            int e1 = min(k + 1, end - 1), e2 = min(k + 2, end - 1);
            int e3 = min(k + 3, end - 1), e4 = min(k + 4, end - 1);
            int e5 = min(k + 5, end - 1), e6 = min(k + 6, end - 1);
            int e7 = min(k + 7, end - 1);
            int s0 = csr[k],  s1 = csr[e1], s2 = csr[e2], s3 = csr[e3];
            int s4 = csr[e4], s5 = csr[e5], s6 = csr[e6], s7 = csr[e7];
            float v0 = y[(size_t)s0 * 64 + lane];
            float v1 = y[(size_t)s1 * 64 + lane];
            float v2 = y[(size_t)s2 * 64 + lane];
            float v3 = y[(size_t)s3 * 64 + lane];
            float v4 = y[(size_t)s4 * 64 + lane];
            float v5 = y[(size_t)s5 * 64 + lane];
            float v6 = y[(size_t)s6 * 64 + lane];
            float v7 = y[(size_t)s7 * 64 + lane];
            a0 += v0;
            a1 += (k + 1 < end) ? v1 : 0.0f;
            a2 += (k + 2 < end) ? v2 : 0.0f;
            a3 += (k + 3 < end) ? v3 : 0.0f;
            a4 += (k + 4 < end) ? v4 : 0.0f;
            a5 += (k + 5 < end) ? v5 : 0.0f;
            a6 += (k + 6 < end) ? v6 : 0.0f;
            a7 += (k + 7 < end) ? v7 : 0.0f;
        }
        float acc = ((a0 + a1) + (a2 + a3)) + ((a4 + a5) + (a6 + a7));
        float val = acc * dinv[n] + b;
        if (RELU) val = fmaxf(val, 0.0f);
        hout[(size_t)n * 64 + lane] = val;
        ps += val;
        pq += val * val;
    }
    __shared__ float S[8][64], Q[8][64];
    S[wid][lane] = ps;
    Q[wid][lane] = pq;
    __syncthreads();
    if (t < 64) {
        float s = 0.0f, q = 0.0f;
#pragma unroll
        for (int w = 0; w < 8; ++w) {
            s += S[w][t];
            q += Q[w][t];
        }
        partials[(size_t)blockIdx.x * 128 + t] = s;
        partials[(size_t)blockIdx.x * 128 + 64 + t] = q;
    }
}

// one block per feature: reduce partials -> mean, rstd
__global__ void k_stats(const float* __restrict__ partials, int nblk,
                        float* __restrict__ mean, float* __restrict__ rstd, float invN) {
    __shared__ float sh[256];
    int f = blockIdx.x, t = threadIdx.x;
    float s = 0.0f, q = 0.0f;
    for (int b = t; b < nblk; b += 256) {
        s += partials[(size_t)b * 128 + f];
        q += partials[(size_t)b * 128 + 64 + f];
    }
    sh[t] = s;
    __syncthreads();
    for (int o = 128; o > 0; o >>= 1) {
        if (t < o) sh[t] += sh[t + o];
        __syncthreads();
    }
    float S = sh[0];
    __syncthreads();
    sh[t] = q;
    __syncthreads();
    for (int o = 128; o > 0; o >>= 1) {
        if (t < o) sh[t] += sh[t + o];
        __syncthreads();
    }
    if (t == 0) {
        float Qs = sh[0];
        float m = S * invN;
        float var = Qs * invN - m * m;
        mean[f] = m;
        rstd[f] = rsqrtf(var + 1e-5f);
    }
}

// mean pool with on-the-fly BN of final layer; batch is sorted -> per-run register accum
__global__ void k_pool(const float* __restrict__ h, const int* __restrict__ batch,
                       const float* __restrict__ mean, const float* __restrict__ rstd,
                       float* __restrict__ psum, float* __restrict__ pcnt) {
    int lane = threadIdx.x;
    int base = blockIdx.x * 64;
    float m = mean[lane], r = rstd[lane];
    int cur = batch[base];
    float acc = 0.0f;
    int runlen = 0;
    for (int i = 0; i < 64; ++i) {
        int n = base + i;
        int g = batch[n];
        if (g != cur) {
            atomicAdd(&psum[cur * 64 + lane], acc);
            if (lane == 0) atomicAdd(&pcnt[cur], (float)runlen);
            acc = 0.0f;
            runlen = 0;
            cur = g;
        }
        acc += (h[(size_t)n * 64 + lane] - m) * r;
        runlen++;
    }
    atomicAdd(&psum[cur * 64 + lane], acc);
    if (lane == 0) atomicAdd(&pcnt[cur], (float)runlen);
}

// logits = pooled @ clfW^T + clfb ; softmax over 16 classes. 1 block x 1024 threads.
__global__ void k_head(const float* __restrict__ psum, const float* __restrict__ pcnt,
                       const float* __restrict__ clfW, const float* __restrict__ clfb,
                       float* __restrict__ out) {
    __shared__ float ps[64 * 64];
    __shared__ float wl[16 * 64];
    __shared__ float ci[64];
    int t = threadIdx.x;
    ((float4*)ps)[t] = ((const float4*)psum)[t];
    if (t < 256) ((float4*)wl)[t] = ((const float4*)clfW)[t];
    if (t < 64) ci[t] = 1.0f / fmaxf(pcnt[t], 1.0f);
    __syncthreads();
    int g = t >> 4, c = t & 15;
    float acc = 0.0f;
#pragma unroll 8
    for (int f = 0; f < 64; ++f) acc += ps[g * 64 + f] * wl[c * 64 + f];
    acc = acc * ci[g] + clfb[c];
    float mx = acc;
    for (int o = 1; o < 16; o <<= 1) mx = fmaxf(mx, __shfl_xor(mx, o, 16));
    float e = __expf(acc - mx);
    float s = e;
    for (int o = 1; o < 16; o <<= 1) s += __shfl_xor(s, o, 16);
    out[t] = e / s;
}

extern "C" void kernel_launch(void* const* d_in, const int* in_sizes, int n_in,
                              void* d_out, int out_size, void* d_ws, size_t ws_size,
                              hipStream_t stream) {
    const float* x    = (const float*)d_in[0];
    const int*   ei   = (const int*)d_in[1];
    const int*   bat  = (const int*)d_in[2];
    const float* W0   = (const float*)d_in[3];
    const float* b0   = (const float*)d_in[4];
    const float* W1   = (const float*)d_in[5];
    const float* b1   = (const float*)d_in[6];
    const float* W2   = (const float*)d_in[7];
    const float* b2   = (const float*)d_in[8];
    const float* clfW = (const float*)d_in[9];
    const float* clfb = (const float*)d_in[10];
    float* out = (float*)d_out;

    const int N = in_sizes[0] / 64;   // 65536
    const int E = in_sizes[1] / 2;    // 1048576
    const int NB = N / 64;            // 1024 buckets

    char* w = (char*)d_ws;
    size_t off = 0;
    auto take = [&](size_t bytes) -> void* {
        off = (off + 255) & ~(size_t)255;
        void* p = w + off;
        off += bytes;
        return p;
    };
    int*   deg      = (int*)take((size_t)N * 4);
    int*   rowptr   = (int*)take((size_t)(N + 1) * 4);
    int*   bcur     = (int*)take((size_t)NB * 4);
    int*   chunk    = (int*)take(256 * 4);
    float* dinv     = (float*)take((size_t)N * 4);
    int*   csr      = (int*)take((size_t)E * 4);
    int*   buck     = (int*)take((size_t)E * 4);
    float* y        = (float*)take((size_t)N * 64 * 4);
    float* hA       = (float*)take((size_t)N * 64 * 4);
    float* hB       = (float*)take((size_t)N * 64 * 4);
    float* partials = (float*)take((size_t)2048 * 128 * 4);
    float* mean     = (float*)take(256);
    float* rstd     = (float*)take(256);
    float* Wf       = (float*)take(4096 * 4);
    float* brow     = (float*)take(256);
    float* psum     = (float*)take(64 * 64 * 4);
    float* pcnt     = (float*)take(64 * 4);

    hipMemsetAsync(deg, 0, (size_t)N * 4, stream);
    hipMemsetAsync(psum, 0, 64 * 64 * 4, stream);
    hipMemsetAsync(pcnt, 0, 64 * 4, stream);

    int eb = (E + 255) / 256;
    k_deg<<<eb, 256, 0, stream>>>(ei, E, deg);
    k_scan1<<<N / 256, 256, 0, stream>>>(deg, rowptr, chunk);
    k_scan2<<<1, 256, 0, stream>>>(chunk);
    k_scan3<<<N / 256, 256, 0, stream>>>(rowptr, chunk, bcur, deg, dinv, N, E);
    k_bkt<<<eb, 256, 0, stream>>>(ei, E, bcur, buck);
    k_place<<<NB, 256, 0, stream>>>(rowptr, buck, csr);

    const float invN = 1.0f / (float)N;

    // layer 0 (input x, no BN on input)
    k_fold<<<1, 256, 0, stream>>>(W0, mean, rstd, 0, Wf, brow);
    k_gemm<<<N / 64, 256, 0, stream>>>(x, Wf, brow, dinv, y);
    k_agg<1><<<2048, 512, 0, stream>>>(y, rowptr, csr, dinv, b0, hA, partials, N);
    k_stats<<<64, 256, 0, stream>>>(partials, 2048, mean, rstd, invN);

    // layer 1
    k_fold<<<1, 256, 0, stream>>>(W1, mean, rstd, 1, Wf, brow);
    k_gemm<<<N / 64, 256, 0, stream>>>(hA, Wf, brow, dinv, y);
    k_agg<1><<<2048, 512, 0, stream>>>(y, rowptr, csr, dinv, b1, hB, partials, N);
    k_stats<<<64, 256, 0, stream>>>(partials, 2048, mean, rstd, invN);

    // layer 2 (no relu)
    k_fold<<<1, 256, 0, stream>>>(W2, mean, rstd, 1, Wf, brow);
    k_gemm<<<N / 64, 256, 0, stream>>>(hB, Wf, brow, dinv, y);
    k_agg<0><<<2048, 512, 0, stream>>>(y, rowptr, csr, dinv, b2, hA, partials, N);
    k_stats<<<64, 256, 0, stream>>>(partials, 2048, mean, rstd, invN);

    // pool (applies final BN on the fly) + head
    k_pool<<<N / 64, 64, 0, stream>>>(hA, bat, mean, rstd, psum, pcnt);
    k_head<<<1, 1024, 0, stream>>>(psum, pcnt, clfW, clfb, out);
}

// Round 4
// 286.810 us; speedup vs baseline: 1.7959x; 1.7959x over previous
//
#include <hip/hip_runtime.h>

// GCN: 3x (GEMM -> CSR aggregate -> bias/relu -> BN-stats), BN folded into next GEMM,
// then segment mean-pool + linear head + softmax.
// Sizes fixed: N=65536 nodes, E=1048576 edges, F=H=64, 64 graphs, 16 classes.
//
// CSR build history: flat scatter (r2: 72MB HBM write, 18x amplification, 82us);
// naive 1024-bucket global-atomic scatter (r3: same-line atomic serialization, 210us).
// Now: LDS-local binning -> one padded global atomic per (block,bucket) -> contiguous
// run writes; per-bucket LDS node-count (replaces k_deg); in-window LDS-cursor place.

#define NBKT 512      // bucket = dst >> 7 (128 nodes per bucket)
#define CAP  4096     // slots per bucket (avg fill 2048; uniform-random safe)
#define BSTRIDE 16    // bcur padded: one counter per 64B line

__global__ void k_binit(int* __restrict__ bcur) {
    int t = blockIdx.x * 256 + threadIdx.x;
    if (t < NBKT) bcur[t * BSTRIDE] = t * CAP;
}

// partition edges into NBKT dst-buckets; entries packed (src<<7)|(dst&127)
__global__ void k_bin(const int* __restrict__ ei, int E, int* __restrict__ bcur,
                      int* __restrict__ buck) {
    __shared__ int sd[4096];
    __shared__ unsigned short bk[4096];
    __shared__ int cnt[NBKT], off[NBKT];
    int t = threadIdx.x;
    int base = blockIdx.x * 4096;
    for (int i = t; i < NBKT; i += 256) cnt[i] = 0;
    __syncthreads();
#pragma unroll
    for (int k = 0; k < 16; ++k) {
        int i = k * 256 + t;
        int e = base + i;
        int s = ei[e], d = ei[E + e];
        sd[i] = (s << 7) | (d & 127);
        int b = d >> 7;
        bk[i] = (unsigned short)b;
        atomicAdd(&cnt[b], 1);
    }
    __syncthreads();
    for (int b = t; b < NBKT; b += 256) {
        int c = cnt[b];
        off[b] = c ? atomicAdd(&bcur[b * BSTRIDE], c) : 0;
    }
    __syncthreads();
#pragma unroll
    for (int k = 0; k < 16; ++k) {
        int i = k * 256 + t;
        int b = bk[i];
        int p = atomicAdd(&off[b], 1);
        buck[p] = sd[i];
    }
}

// per-bucket node-degree count (dense deg writes; no global atomics)
__global__ void k_cnt(const int* __restrict__ bcur, const int* __restrict__ buck,
                      int* __restrict__ deg) {
    __shared__ int dc[128];
    int b = blockIdx.x, t = threadIdx.x;
    if (t < 128) dc[t] = 0;
    __syncthreads();
    int beg = b * CAP;
    int end = bcur[b * BSTRIDE];
    for (int i = beg + t; i < end; i += 256) atomicAdd(&dc[buck[i] & 127], 1);
    __syncthreads();
    if (t < 128) deg[b * 128 + t] = dc[t];
}

__global__ void k_scan1(const int* __restrict__ deg, int* __restrict__ rowptr,
                        int* __restrict__ chunk) {
    __shared__ int s[256];
    int t = threadIdx.x, b = blockIdx.x;
    int v = deg[b * 256 + t];
    s[t] = v;
    __syncthreads();
    for (int o = 1; o < 256; o <<= 1) {
        int x = (t >= o) ? s[t - o] : 0;
        __syncthreads();
        s[t] += x;
        __syncthreads();
    }
    rowptr[b * 256 + t] = s[t] - v;  // local exclusive
    if (t == 255) chunk[b] = s[255];
}

__global__ void k_scan2(int* __restrict__ chunk) {
    __shared__ int s[256];
    int t = threadIdx.x;
    int v = chunk[t];
    s[t] = v;
    __syncthreads();
    for (int o = 1; o < 256; o <<= 1) {
        int x = (t >= o) ? s[t - o] : 0;
        __syncthreads();
        s[t] += x;
        __syncthreads();
    }
    chunk[t] = s[t] - v;  // exclusive
}

__global__ void k_scan3(int* __restrict__ rowptr, const int* __restrict__ chunk,
                        const int* __restrict__ deg, float* __restrict__ dinv,
                        int N, int E) {
    int n = blockIdx.x * 256 + threadIdx.x;
    int r = rowptr[n] + chunk[blockIdx.x];
    rowptr[n] = r;
    dinv[n] = rsqrtf((float)(deg[n] + 1));  // +1 self loop
    if (n == 0) rowptr[N] = E;
}

// scatter csr within the bucket's contiguous window (LDS cursors, dense dirty lines)
__global__ void k_place(const int* __restrict__ bcur, const int* __restrict__ buck,
                        const int* __restrict__ rowptr, int* __restrict__ csr) {
    __shared__ int cur[128];
    int b = blockIdx.x, t = threadIdx.x;
    if (t < 128) cur[t] = rowptr[b * 128 + t];
    __syncthreads();
    int beg = b * CAP, end = bcur[b * BSTRIDE];
    for (int i = beg + t; i < end; i += 256) {
        int v = buck[i];
        int p = atomicAdd(&cur[v & 127], 1);
        csr[p] = v >> 7;
    }
}

// Fold BN(prev layer) into W: Wf[f][j] = rstd[f]*W[f][j]; brow[j] = -sum_f mean[f]*rstd[f]*W[f][j]
__global__ void k_fold(const float* __restrict__ W, const float* __restrict__ mean,
                       const float* __restrict__ rstd, int has_stats,
                       float* __restrict__ Wf, float* __restrict__ brow) {
    __shared__ float sm[64], sr[64];
    int t = threadIdx.x;
    if (t < 64) {
        sm[t] = has_stats ? mean[t] : 0.0f;
        sr[t] = has_stats ? rstd[t] : 1.0f;
    }
    __syncthreads();
    for (int i = t; i < 4096; i += 256) {
        int f = i >> 6;
        Wf[i] = sr[f] * W[i];
    }
    if (t < 64) {
        float acc = 0.0f;
        for (int f = 0; f < 64; ++f) acc += sm[f] * sr[f] * W[f * 64 + t];
        brow[t] = -acc;
    }
}

// y[n][j] = dinv[n] * ( sum_f h[n][f]*Wf[f][j] + brow[j] )
// block 256 threads, 64 rows/block; thread = 4x4 output tile
__global__ void k_gemm(const float* __restrict__ h, const float* __restrict__ Wf,
                       const float* __restrict__ brow, const float* __restrict__ dinv,
                       float* __restrict__ y) {
    __shared__ float Ws[4096];        // [f][c] 64x64
    __shared__ float hs[64 * 65];     // [row][f], stride 65
    int t = threadIdx.x;
    int rowBase = blockIdx.x * 64;
#pragma unroll
    for (int k = 0; k < 4; ++k)
        ((float4*)Ws)[t + k * 256] = ((const float4*)Wf)[t + k * 256];
#pragma unroll
    for (int k = 0; k < 4; ++k) {
        int i = t + k * 256;              // 0..1023 float4s of the h block
        int row = i >> 4, c4 = i & 15;
        float4 v = ((const float4*)(h + (size_t)rowBase * 64))[i];
        float* dst = &hs[row * 65 + c4 * 4];
        dst[0] = v.x; dst[1] = v.y; dst[2] = v.z; dst[3] = v.w;
    }
    __syncthreads();
    int rg = t >> 4;   // 0..15
    int cg = t & 15;   // 0..15
    float4 a0, a1, a2, a3;
    {
        float bx = brow[cg * 4 + 0], by = brow[cg * 4 + 1];
        float bz = brow[cg * 4 + 2], bw = brow[cg * 4 + 3];
        a0 = {bx, by, bz, bw}; a1 = a0; a2 = a0; a3 = a0;
    }
    const float* h0 = &hs[(rg * 4 + 0) * 65];
    const float* h1 = &hs[(rg * 4 + 1) * 65];
    const float* h2 = &hs[(rg * 4 + 2) * 65];
    const float* h3 = &hs[(rg * 4 + 3) * 65];
#pragma unroll 4
    for (int f = 0; f < 64; ++f) {
        float4 wv = ((float4*)Ws)[f * 16 + cg];
        float v0 = h0[f], v1 = h1[f], v2 = h2[f], v3 = h3[f];
        a0.x += v0 * wv.x; a0.y += v0 * wv.y; a0.z += v0 * wv.z; a0.w += v0 * wv.w;
        a1.x += v1 * wv.x; a1.y += v1 * wv.y; a1.z += v1 * wv.z; a1.w += v1 * wv.w;
        a2.x += v2 * wv.x; a2.y += v2 * wv.y; a2.z += v2 * wv.z; a2.w += v2 * wv.w;
        a3.x += v3 * wv.x; a3.y += v3 * wv.y; a3.z += v3 * wv.z; a3.w += v3 * wv.w;
    }
    float d0 = dinv[rowBase + rg * 4 + 0];
    float d1 = dinv[rowBase + rg * 4 + 1];
    float d2 = dinv[rowBase + rg * 4 + 2];
    float d3 = dinv[rowBase + rg * 4 + 3];
    a0.x *= d0; a0.y *= d0; a0.z *= d0; a0.w *= d0;
    a1.x *= d1; a1.y *= d1; a1.z *= d1; a1.w *= d1;
    a2.x *= d2; a2.y *= d2; a2.z *= d2; a2.w *= d2;
    a3.x *= d3; a3.y *= d3; a3.z *= d3; a3.w *= d3;
    float4* y4 = (float4*)y;
    size_t ob = (size_t)(rowBase + rg * 4) * 16 + cg;
    y4[ob + 0]  = a0;
    y4[ob + 16] = a1;
    y4[ob + 32] = a2;
    y4[ob + 48] = a3;
}

// out[n] = relu?( dinv[n]*(y[n] + sum_{src in csr[n]} y[src]) + bias )
// 8-wide unrolled gather with clamped-index predication: 8 loads in flight per wave.
template <int RELU>
__global__ void k_agg(const float* __restrict__ y, const int* __restrict__ rowptr,
                      const int* __restrict__ csr, const float* __restrict__ dinv,
                      const float* __restrict__ bias, float* __restrict__ hout,
                      float* __restrict__ partials, int N) {
    int t = threadIdx.x;
    int lane = t & 63;
    int wid = t >> 6;                       // 0..7
    int gwave = blockIdx.x * 8 + wid;       // 0..16383
    float b = bias[lane];
    float ps = 0.0f, pq = 0.0f;
    for (int n = gwave; n < N; n += 16384) {
        int beg = rowptr[n], end = rowptr[n + 1];
        float a0 = y[(size_t)n * 64 + lane];
        float a1 = 0.0f, a2 = 0.0f, a3 = 0.0f;
        float a4 = 0.0f, a5 = 0.0f, a6 = 0.0f, a7 = 0.0f;
        for (int k = beg; k < end; k += 8) {
            int e1 = min(k + 1, end - 1), e2 = min(k + 2, end - 1);
            int e3 = min(k + 3, end - 1), e4 = min(k + 4, end - 1);
            int e5 = min(k + 5, end - 1), e6 = min(k + 6, end - 1);
            int e7 = min(k + 7, end - 1);
            int s0 = csr[k],  s1 = csr[e1], s2 = csr[e2], s3 = csr[e3];
            int s4 = csr[e4], s5 = csr[e5], s6 = csr[e6], s7 = csr[e7];
            float v0 = y[(size_t)s0 * 64 + lane];
            float v1 = y[(size_t)s1 * 64 + lane];
            float v2 = y[(size_t)s2 * 64 + lane];
            float v3 = y[(size_t)s3 * 64 + lane];
            float v4 = y[(size_t)s4 * 64 + lane];
            float v5 = y[(size_t)s5 * 64 + lane];
            float v6 = y[(size_t)s6 * 64 + lane];
            float v7 = y[(size_t)s7 * 64 + lane];
            a0 += v0;
            a1 += (k + 1 < end) ? v1 : 0.0f;
            a2 += (k + 2 < end) ? v2 : 0.0f;
            a3 += (k + 3 < end) ? v3 : 0.0f;
            a4 += (k + 4 < end) ? v4 : 0.0f;
            a5 += (k + 5 < end) ? v5 : 0.0f;
            a6 += (k + 6 < end) ? v6 : 0.0f;
            a7 += (k + 7 < end) ? v7 : 0.0f;
        }
        float acc = ((a0 + a1) + (a2 + a3)) + ((a4 + a5) + (a6 + a7));
        float val = acc * dinv[n] + b;
        if (RELU) val = fmaxf(val, 0.0f);
        hout[(size_t)n * 64 + lane] = val;
        ps += val;
        pq += val * val;
    }
    __shared__ float S[8][64], Q[8][64];
    S[wid][lane] = ps;
    Q[wid][lane] = pq;
    __syncthreads();
    if (t < 64) {
        float s = 0.0f, q = 0.0f;
#pragma unroll
        for (int w = 0; w < 8; ++w) {
            s += S[w][t];
            q += Q[w][t];
        }
        partials[(size_t)blockIdx.x * 128 + t] = s;
        partials[(size_t)blockIdx.x * 128 + 64 + t] = q;
    }
}

// one block per feature: reduce partials -> mean, rstd
__global__ void k_stats(const float* __restrict__ partials, int nblk,
                        float* __restrict__ mean, float* __restrict__ rstd, float invN) {
    __shared__ float sh[256];
    int f = blockIdx.x, t = threadIdx.x;
    float s = 0.0f, q = 0.0f;
    for (int b = t; b < nblk; b += 256) {
        s += partials[(size_t)b * 128 + f];
        q += partials[(size_t)b * 128 + 64 + f];
    }
    sh[t] = s;
    __syncthreads();
    for (int o = 128; o > 0; o >>= 1) {
        if (t < o) sh[t] += sh[t + o];
        __syncthreads();
    }
    float S = sh[0];
    __syncthreads();
    sh[t] = q;
    __syncthreads();
    for (int o = 128; o > 0; o >>= 1) {
        if (t < o) sh[t] += sh[t + o];
        __syncthreads();
    }
    if (t == 0) {
        float Qs = sh[0];
        float m = S * invN;
        float var = Qs * invN - m * m;
        mean[f] = m;
        rstd[f] = rsqrtf(var + 1e-5f);
    }
}

// mean pool with on-the-fly BN of final layer; batch is sorted -> per-run register accum
__global__ void k_pool(const float* __restrict__ h, const int* __restrict__ batch,
                       const float* __restrict__ mean, const float* __restrict__ rstd,
                       float* __restrict__ psum, float* __restrict__ pcnt) {
    int lane = threadIdx.x;
    int base = blockIdx.x * 64;
    float m = mean[lane], r = rstd[lane];
    int cur = batch[base];
    float acc = 0.0f;
    int runlen = 0;
    for (int i = 0; i < 64; ++i) {
        int n = base + i;
        int g = batch[n];
        if (g != cur) {
            atomicAdd(&psum[cur * 64 + lane], acc);
            if (lane == 0) atomicAdd(&pcnt[cur], (float)runlen);
            acc = 0.0f;
            runlen = 0;
            cur = g;
        }
        acc += (h[(size_t)n * 64 + lane] - m) * r;
        runlen++;
    }
    atomicAdd(&psum[cur * 64 + lane], acc);
    if (lane == 0) atomicAdd(&pcnt[cur], (float)runlen);
}

// logits = pooled @ clfW^T + clfb ; softmax over 16 classes. 1 block x 1024 threads.
__global__ void k_head(const float* __restrict__ psum, const float* __restrict__ pcnt,
                       const float* __restrict__ clfW, const float* __restrict__ clfb,
                       float* __restrict__ out) {
    __shared__ float ps[64 * 64];
    __shared__ float wl[16 * 64];
    __shared__ float ci[64];
    int t = threadIdx.x;
    ((float4*)ps)[t] = ((const float4*)psum)[t];
    if (t < 256) ((float4*)wl)[t] = ((const float4*)clfW)[t];
    if (t < 64) ci[t] = 1.0f / fmaxf(pcnt[t], 1.0f);
    __syncthreads();
    int g = t >> 4, c = t & 15;
    float acc = 0.0f;
#pragma unroll 8
    for (int f = 0; f < 64; ++f) acc += ps[g * 64 + f] * wl[c * 64 + f];
    acc = acc * ci[g] + clfb[c];
    float mx = acc;
    for (int o = 1; o < 16; o <<= 1) mx = fmaxf(mx, __shfl_xor(mx, o, 16));
    float e = __expf(acc - mx);
    float s = e;
    for (int o = 1; o < 16; o <<= 1) s += __shfl_xor(s, o, 16);
    out[t] = e / s;
}

extern "C" void kernel_launch(void* const* d_in, const int* in_sizes, int n_in,
                              void* d_out, int out_size, void* d_ws, size_t ws_size,
                              hipStream_t stream) {
    const float* x    = (const float*)d_in[0];
    const int*   ei   = (const int*)d_in[1];
    const int*   bat  = (const int*)d_in[2];
    const float* W0   = (const float*)d_in[3];
    const float* b0   = (const float*)d_in[4];
    const float* W1   = (const float*)d_in[5];
    const float* b1   = (const float*)d_in[6];
    const float* W2   = (const float*)d_in[7];
    const float* b2   = (const float*)d_in[8];
    const float* clfW = (const float*)d_in[9];
    const float* clfb = (const float*)d_in[10];
    float* out = (float*)d_out;

    const int N = in_sizes[0] / 64;   // 65536
    const int E = in_sizes[1] / 2;    // 1048576

    char* w = (char*)d_ws;
    size_t off = 0;
    auto take = [&](size_t bytes) -> void* {
        off = (off + 255) & ~(size_t)255;
        void* p = w + off;
        off += bytes;
        return p;
    };
    int*   deg      = (int*)take((size_t)N * 4);
    int*   rowptr   = (int*)take((size_t)(N + 1) * 4);
    int*   bcur     = (int*)take((size_t)NBKT * BSTRIDE * 4);
    int*   chunk    = (int*)take(256 * 4);
    float* dinv     = (float*)take((size_t)N * 4);
    int*   csr      = (int*)take((size_t)E * 4);
    float* y        = (float*)take((size_t)N * 64 * 4);
    float* hA       = (float*)take((size_t)N * 64 * 4);
    float* hB       = (float*)take((size_t)N * 64 * 4);
    float* partials = (float*)take((size_t)2048 * 128 * 4);
    float* mean     = (float*)take(256);
    float* rstd     = (float*)take(256);
    float* Wf       = (float*)take(4096 * 4);
    float* brow     = (float*)take(256);
    float* psum     = (float*)take(64 * 64 * 4);
    float* pcnt     = (float*)take(64 * 4);
    // buck (NBKT*CAP ints = 8MB) overlaid on hB (16MB): buck dead after k_place,
    // hB first written in layer-1 k_agg.
    int* buck = (int*)hB;

    hipMemsetAsync(psum, 0, 64 * 64 * 4, stream);
    hipMemsetAsync(pcnt, 0, 64 * 4, stream);

    k_binit<<<(NBKT + 255) / 256, 256, 0, stream>>>(bcur);
    k_bin<<<E / 4096, 256, 0, stream>>>(ei, E, bcur, buck);
    k_cnt<<<NBKT, 256, 0, stream>>>(bcur, buck, deg);
    k_scan1<<<N / 256, 256, 0, stream>>>(deg, rowptr, chunk);
    k_scan2<<<1, 256, 0, stream>>>(chunk);
    k_scan3<<<N / 256, 256, 0, stream>>>(rowptr, chunk, deg, dinv, N, E);
    k_place<<<NBKT, 256, 0, stream>>>(bcur, buck, rowptr, csr);

    const float invN = 1.0f / (float)N;

    // layer 0 (input x, no BN on input)
    k_fold<<<1, 256, 0, stream>>>(W0, mean, rstd, 0, Wf, brow);
    k_gemm<<<N / 64, 256, 0, stream>>>(x, Wf, brow, dinv, y);
    k_agg<1><<<2048, 512, 0, stream>>>(y, rowptr, csr, dinv, b0, hA, partials, N);
    k_stats<<<64, 256, 0, stream>>>(partials, 2048, mean, rstd, invN);

    // layer 1
    k_fold<<<1, 256, 0, stream>>>(W1, mean, rstd, 1, Wf, brow);
    k_gemm<<<N / 64, 256, 0, stream>>>(hA, Wf, brow, dinv, y);
    k_agg<1><<<2048, 512, 0, stream>>>(y, rowptr, csr, dinv, b1, hB, partials, N);
    k_stats<<<64, 256, 0, stream>>>(partials, 2048, mean, rstd, invN);

    // layer 2 (no relu)
    k_fold<<<1, 256, 0, stream>>>(W2, mean, rstd, 1, Wf, brow);
    k_gemm<<<N / 64, 256, 0, stream>>>(hB, Wf, brow, dinv, y);
    k_agg<0><<<2048, 512, 0, stream>>>(y, rowptr, csr, dinv, b2, hA, partials, N);
    k_stats<<<64, 256, 0, stream>>>(partials, 2048, mean, rstd, invN);

    // pool (applies final BN on the fly) + head
    k_pool<<<N / 64, 64, 0, stream>>>(hA, bat, mean, rstd, psum, pcnt);
    k_head<<<1, 1024, 0, stream>>>(psum, pcnt, clfW, clfb, out);
}

// Round 5
// 263.865 us; speedup vs baseline: 1.9521x; 1.0870x over previous
//
#include <hip/hip_runtime.h>
#include <hip/hip_fp16.h>

// GCN: 3x (GEMM -> CSR aggregate -> bias/relu -> BN-stats), BN folded into next GEMM,
// then segment mean-pool + linear head + softmax.
// Sizes fixed: N=65536 nodes, E=1048576 edges, F=H=64, 64 graphs, 16 classes.
//
// CSR build: LDS-local binning -> one padded global atomic per (block,bucket) ->
// contiguous run writes; per-bucket LDS node-count; in-window LDS-cursor place.
// (r2: flat scatter 18x write amplification; r3: same-line atomic serialization.)
// r5: y and inter-layer activations in fp16 -> gather/write bytes halved
// (r4 k_agg: FETCH 113MB, 2.78TB/s apparent, VALU 43% -> traffic-dominated).

#define NBKT 512      // bucket = dst >> 7 (128 nodes per bucket)
#define CAP  4096     // slots per bucket (avg fill 2048; uniform-random safe)
#define BSTRIDE 16    // bcur padded: one counter per 64B line

__device__ inline unsigned pack2h(float a, float b) {
    __half ha = __float2half_rn(a), hb = __float2half_rn(b);
    unsigned short ua = *(unsigned short*)&ha, ub = *(unsigned short*)&hb;
    return (unsigned)ua | ((unsigned)ub << 16);
}

__global__ void k_binit(int* __restrict__ bcur) {
    int t = blockIdx.x * 256 + threadIdx.x;
    if (t < NBKT) bcur[t * BSTRIDE] = t * CAP;
}

// partition edges into NBKT dst-buckets; entries packed (src<<7)|(dst&127)
__global__ void k_bin(const int* __restrict__ ei, int E, int* __restrict__ bcur,
                      int* __restrict__ buck) {
    __shared__ int sd[4096];
    __shared__ unsigned short bk[4096];
    __shared__ int cnt[NBKT], off[NBKT];
    int t = threadIdx.x;
    int base = blockIdx.x * 4096;
    for (int i = t; i < NBKT; i += 256) cnt[i] = 0;
    __syncthreads();
#pragma unroll
    for (int k = 0; k < 16; ++k) {
        int i = k * 256 + t;
        int e = base + i;
        int s = ei[e], d = ei[E + e];
        sd[i] = (s << 7) | (d & 127);
        int b = d >> 7;
        bk[i] = (unsigned short)b;
        atomicAdd(&cnt[b], 1);
    }
    __syncthreads();
    for (int b = t; b < NBKT; b += 256) {
        int c = cnt[b];
        off[b] = c ? atomicAdd(&bcur[b * BSTRIDE], c) : 0;
    }
    __syncthreads();
#pragma unroll
    for (int k = 0; k < 16; ++k) {
        int i = k * 256 + t;
        int b = bk[i];
        int p = atomicAdd(&off[b], 1);
        buck[p] = sd[i];
    }
}

// per-bucket node-degree count (dense deg writes; no global atomics)
__global__ void k_cnt(const int* __restrict__ bcur, const int* __restrict__ buck,
                      int* __restrict__ deg) {
    __shared__ int dc[128];
    int b = blockIdx.x, t = threadIdx.x;
    if (t < 128) dc[t] = 0;
    __syncthreads();
    int beg = b * CAP;
    int end = bcur[b * BSTRIDE];
    for (int i = beg + t; i < end; i += 256) atomicAdd(&dc[buck[i] & 127], 1);
    __syncthreads();
    if (t < 128) deg[b * 128 + t] = dc[t];
}

__global__ void k_scan1(const int* __restrict__ deg, int* __restrict__ rowptr,
                        int* __restrict__ chunk) {
    __shared__ int s[256];
    int t = threadIdx.x, b = blockIdx.x;
    int v = deg[b * 256 + t];
    s[t] = v;
    __syncthreads();
    for (int o = 1; o < 256; o <<= 1) {
        int x = (t >= o) ? s[t - o] : 0;
        __syncthreads();
        s[t] += x;
        __syncthreads();
    }
    rowptr[b * 256 + t] = s[t] - v;  // local exclusive
    if (t == 255) chunk[b] = s[255];
}

__global__ void k_scan2(int* __restrict__ chunk) {
    __shared__ int s[256];
    int t = threadIdx.x;
    int v = chunk[t];
    s[t] = v;
    __syncthreads();
    for (int o = 1; o < 256; o <<= 1) {
        int x = (t >= o) ? s[t - o] : 0;
        __syncthreads();
        s[t] += x;
        __syncthreads();
    }
    chunk[t] = s[t] - v;  // exclusive
}

__global__ void k_scan3(int* __restrict__ rowptr, const int* __restrict__ chunk,
                        const int* __restrict__ deg, float* __restrict__ dinv,
                        int N, int E) {
    int n = blockIdx.x * 256 + threadIdx.x;
    int r = rowptr[n] + chunk[blockIdx.x];
    rowptr[n] = r;
    dinv[n] = rsqrtf((float)(deg[n] + 1));  // +1 self loop
    if (n == 0) rowptr[N] = E;
}

// scatter csr within the bucket's contiguous window (LDS cursors, dense dirty lines)
__global__ void k_place(const int* __restrict__ bcur, const int* __restrict__ buck,
                        const int* __restrict__ rowptr, int* __restrict__ csr) {
    __shared__ int cur[128];
    int b = blockIdx.x, t = threadIdx.x;
    if (t < 128) cur[t] = rowptr[b * 128 + t];
    __syncthreads();
    int beg = b * CAP, end = bcur[b * BSTRIDE];
    for (int i = beg + t; i < end; i += 256) {
        int v = buck[i];
        int p = atomicAdd(&cur[v & 127], 1);
        csr[p] = v >> 7;
    }
}

// Fold BN(prev layer) into W: Wf[f][j] = rstd[f]*W[f][j]; brow[j] = -sum_f mean[f]*rstd[f]*W[f][j]
__global__ void k_fold(const float* __restrict__ W, const float* __restrict__ mean,
                       const float* __restrict__ rstd, int has_stats,
                       float* __restrict__ Wf, float* __restrict__ brow) {
    __shared__ float sm[64], sr[64];
    int t = threadIdx.x;
    if (t < 64) {
        sm[t] = has_stats ? mean[t] : 0.0f;
        sr[t] = has_stats ? rstd[t] : 1.0f;
    }
    __syncthreads();
    for (int i = t; i < 4096; i += 256) {
        int f = i >> 6;
        Wf[i] = sr[f] * W[i];
    }
    if (t < 64) {
        float acc = 0.0f;
        for (int f = 0; f < 64; ++f) acc += sm[f] * sr[f] * W[f * 64 + t];
        brow[t] = -acc;
    }
}

// y[n][j] = fp16( dinv[n] * ( sum_f h[n][f]*Wf[f][j] + brow[j] ) )
// block 256 threads, 64 rows/block; thread = 4x4 output tile.
// HIN=0: h is fp32 (layer 0 input x); HIN=1: h is fp16 (hA/hB).
template <int HIN>
__global__ void k_gemm(const void* __restrict__ hv, const float* __restrict__ Wf,
                       const float* __restrict__ brow, const float* __restrict__ dinv,
                       __half* __restrict__ y) {
    __shared__ float Ws[4096];        // [f][c] 64x64
    __shared__ float hs[64 * 65];     // [row][f], stride 65
    int t = threadIdx.x;
    int rowBase = blockIdx.x * 64;
#pragma unroll
    for (int k = 0; k < 4; ++k)
        ((float4*)Ws)[t + k * 256] = ((const float4*)Wf)[t + k * 256];
    if (HIN) {
        const uint4* src = (const uint4*)((const __half*)hv + (size_t)rowBase * 64);
#pragma unroll
        for (int k = 0; k < 2; ++k) {
            int i = t + k * 256;          // 0..511 uint4s; each = 8 halves
            int row = i >> 3, c8 = i & 7;
            uint4 u = src[i];
            const __half2* hp = (const __half2*)&u;
            float* dst = &hs[row * 65 + c8 * 8];
#pragma unroll
            for (int j = 0; j < 4; ++j) {
                dst[2 * j + 0] = __low2float(hp[j]);
                dst[2 * j + 1] = __high2float(hp[j]);
            }
        }
    } else {
        const float4* src = (const float4*)((const float*)hv + (size_t)rowBase * 64);
#pragma unroll
        for (int k = 0; k < 4; ++k) {
            int i = t + k * 256;          // 0..1023 float4s
            int row = i >> 4, c4 = i & 15;
            float4 v = src[i];
            float* dst = &hs[row * 65 + c4 * 4];
            dst[0] = v.x; dst[1] = v.y; dst[2] = v.z; dst[3] = v.w;
        }
    }
    __syncthreads();
    int rg = t >> 4;   // 0..15
    int cg = t & 15;   // 0..15
    float4 a0, a1, a2, a3;
    {
        float bx = brow[cg * 4 + 0], by = brow[cg * 4 + 1];
        float bz = brow[cg * 4 + 2], bw = brow[cg * 4 + 3];
        a0 = {bx, by, bz, bw}; a1 = a0; a2 = a0; a3 = a0;
    }
    const float* h0 = &hs[(rg * 4 + 0) * 65];
    const float* h1 = &hs[(rg * 4 + 1) * 65];
    const float* h2 = &hs[(rg * 4 + 2) * 65];
    const float* h3 = &hs[(rg * 4 + 3) * 65];
#pragma unroll 4
    for (int f = 0; f < 64; ++f) {
        float4 wv = ((float4*)Ws)[f * 16 + cg];
        float v0 = h0[f], v1 = h1[f], v2 = h2[f], v3 = h3[f];
        a0.x += v0 * wv.x; a0.y += v0 * wv.y; a0.z += v0 * wv.z; a0.w += v0 * wv.w;
        a1.x += v1 * wv.x; a1.y += v1 * wv.y; a1.z += v1 * wv.z; a1.w += v1 * wv.w;
        a2.x += v2 * wv.x; a2.y += v2 * wv.y; a2.z += v2 * wv.z; a2.w += v2 * wv.w;
        a3.x += v3 * wv.x; a3.y += v3 * wv.y; a3.z += v3 * wv.z; a3.w += v3 * wv.w;
    }
    float d0 = dinv[rowBase + rg * 4 + 0];
    float d1 = dinv[rowBase + rg * 4 + 1];
    float d2 = dinv[rowBase + rg * 4 + 2];
    float d3 = dinv[rowBase + rg * 4 + 3];
    uint2* y2 = (uint2*)y;
    size_t ob = (size_t)(rowBase + rg * 4) * 16 + cg;
    y2[ob + 0]  = {pack2h(a0.x * d0, a0.y * d0), pack2h(a0.z * d0, a0.w * d0)};
    y2[ob + 16] = {pack2h(a1.x * d1, a1.y * d1), pack2h(a1.z * d1, a1.w * d1)};
    y2[ob + 32] = {pack2h(a2.x * d2, a2.y * d2), pack2h(a2.z * d2, a2.w * d2)};
    y2[ob + 48] = {pack2h(a3.x * d3, a3.y * d3), pack2h(a3.z * d3, a3.w * d3)};
}

// out[n] = relu?( dinv[n]*(y[n] + sum_{src in csr[n]} y[src]) + bias ), stored fp16.
// 8-wide unrolled gather with clamped-index predication: 8 loads in flight per wave.
// BN partial sums computed on fp32 val (pre-rounding).
template <int RELU>
__global__ void k_agg(const __half* __restrict__ y, const int* __restrict__ rowptr,
                      const int* __restrict__ csr, const float* __restrict__ dinv,
                      const float* __restrict__ bias, __half* __restrict__ hout,
                      float* __restrict__ partials, int N) {
    int t = threadIdx.x;
    int lane = t & 63;
    int wid = t >> 6;                       // 0..7
    int gwave = blockIdx.x * 8 + wid;       // 0..16383
    float b = bias[lane];
    float ps = 0.0f, pq = 0.0f;
    for (int n = gwave; n < N; n += 16384) {
        int beg = rowptr[n], end = rowptr[n + 1];
        float a0 = __half2float(y[(size_t)n * 64 + lane]);
        float a1 = 0.0f, a2 = 0.0f, a3 = 0.0f;
        float a4 = 0.0f, a5 = 0.0f, a6 = 0.0f, a7 = 0.0f;
        for (int k = beg; k < end; k += 8) {
            int e1 = min(k + 1, end - 1), e2 = min(k + 2, end - 1);
            int e3 = min(k + 3, end - 1), e4 = min(k + 4, end - 1);
            int e5 = min(k + 5, end - 1), e6 = min(k + 6, end - 1);
            int e7 = min(k + 7, end - 1);
            int s0 = csr[k],  s1 = csr[e1], s2 = csr[e2], s3 = csr[e3];
            int s4 = csr[e4], s5 = csr[e5], s6 = csr[e6], s7 = csr[e7];
            float v0 = __half2float(y[(size_t)s0 * 64 + lane]);
            float v1 = __half2float(y[(size_t)s1 * 64 + lane]);
            float v2 = __half2float(y[(size_t)s2 * 64 + lane]);
            float v3 = __half2float(y[(size_t)s3 * 64 + lane]);
            float v4 = __half2float(y[(size_t)s4 * 64 + lane]);
            float v5 = __half2float(y[(size_t)s5 * 64 + lane]);
            float v6 = __half2float(y[(size_t)s6 * 64 + lane]);
            float v7 = __half2float(y[(size_t)s7 * 64 + lane]);
            a0 += v0;
            a1 += (k + 1 < end) ? v1 : 0.0f;
            a2 += (k + 2 < end) ? v2 : 0.0f;
            a3 += (k + 3 < end) ? v3 : 0.0f;
            a4 += (k + 4 < end) ? v4 : 0.0f;
            a5 += (k + 5 < end) ? v5 : 0.0f;
            a6 += (k + 6 < end) ? v6 : 0.0f;
            a7 += (k + 7 < end) ? v7 : 0.0f;
        }
        float acc = ((a0 + a1) + (a2 + a3)) + ((a4 + a5) + (a6 + a7));
        float val = acc * dinv[n] + b;
        if (RELU) val = fmaxf(val, 0.0f);
        hout[(size_t)n * 64 + lane] = __float2half_rn(val);
        ps += val;
        pq += val * val;
    }
    __shared__ float S[8][64], Q[8][64];
    S[wid][lane] = ps;
    Q[wid][lane] = pq;
    __syncthreads();
    if (t < 64) {
        float s = 0.0f, q = 0.0f;
#pragma unroll
        for (int w = 0; w < 8; ++w) {
            s += S[w][t];
            q += Q[w][t];
        }
        partials[(size_t)blockIdx.x * 128 + t] = s;
        partials[(size_t)blockIdx.x * 128 + 64 + t] = q;
    }
}

// one block per feature: reduce partials -> mean, rstd
__global__ void k_stats(const float* __restrict__ partials, int nblk,
                        float* __restrict__ mean, float* __restrict__ rstd, float invN) {
    __shared__ float sh[256];
    int f = blockIdx.x, t = threadIdx.x;
    float s = 0.0f, q = 0.0f;
    for (int b = t; b < nblk; b += 256) {
        s += partials[(size_t)b * 128 + f];
        q += partials[(size_t)b * 128 + 64 + f];
    }
    sh[t] = s;
    __syncthreads();
    for (int o = 128; o > 0; o >>= 1) {
        if (t < o) sh[t] += sh[t + o];
        __syncthreads();
    }
    float S = sh[0];
    __syncthreads();
    sh[t] = q;
    __syncthreads();
    for (int o = 128; o > 0; o >>= 1) {
        if (t < o) sh[t] += sh[t + o];
        __syncthreads();
    }
    if (t == 0) {
        float Qs = sh[0];
        float m = S * invN;
        float var = Qs * invN - m * m;
        mean[f] = m;
        rstd[f] = rsqrtf(var + 1e-5f);
    }
}

// mean pool with on-the-fly BN of final layer; batch is sorted -> per-run register accum
__global__ void k_pool(const __half* __restrict__ h, const int* __restrict__ batch,
                       const float* __restrict__ mean, const float* __restrict__ rstd,
                       float* __restrict__ psum, float* __restrict__ pcnt) {
    int lane = threadIdx.x;
    int base = blockIdx.x * 64;
    float m = mean[lane], r = rstd[lane];
    int cur = batch[base];
    float acc = 0.0f;
    int runlen = 0;
    for (int i = 0; i < 64; ++i) {
        int n = base + i;
        int g = batch[n];
        if (g != cur) {
            atomicAdd(&psum[cur * 64 + lane], acc);
            if (lane == 0) atomicAdd(&pcnt[cur], (float)runlen);
            acc = 0.0f;
            runlen = 0;
            cur = g;
        }
        acc += (__half2float(h[(size_t)n * 64 + lane]) - m) * r;
        runlen++;
    }
    atomicAdd(&psum[cur * 64 + lane], acc);
    if (lane == 0) atomicAdd(&pcnt[cur], (float)runlen);
}

// logits = pooled @ clfW^T + clfb ; softmax over 16 classes. 1 block x 1024 threads.
__global__ void k_head(const float* __restrict__ psum, const float* __restrict__ pcnt,
                       const float* __restrict__ clfW, const float* __restrict__ clfb,
                       float* __restrict__ out) {
    __shared__ float ps[64 * 64];
    __shared__ float wl[16 * 64];
    __shared__ float ci[64];
    int t = threadIdx.x;
    ((float4*)ps)[t] = ((const float4*)psum)[t];
    if (t < 256) ((float4*)wl)[t] = ((const float4*)clfW)[t];
    if (t < 64) ci[t] = 1.0f / fmaxf(pcnt[t], 1.0f);
    __syncthreads();
    int g = t >> 4, c = t & 15;
    float acc = 0.0f;
#pragma unroll 8
    for (int f = 0; f < 64; ++f) acc += ps[g * 64 + f] * wl[c * 64 + f];
    acc = acc * ci[g] + clfb[c];
    float mx = acc;
    for (int o = 1; o < 16; o <<= 1) mx = fmaxf(mx, __shfl_xor(mx, o, 16));
    float e = __expf(acc - mx);
    float s = e;
    for (int o = 1; o < 16; o <<= 1) s += __shfl_xor(s, o, 16);
    out[t] = e / s;
}

extern "C" void kernel_launch(void* const* d_in, const int* in_sizes, int n_in,
                              void* d_out, int out_size, void* d_ws, size_t ws_size,
                              hipStream_t stream) {
    const float* x    = (const float*)d_in[0];
    const int*   ei   = (const int*)d_in[1];
    const int*   bat  = (const int*)d_in[2];
    const float* W0   = (const float*)d_in[3];
    const float* b0   = (const float*)d_in[4];
    const float* W1   = (const float*)d_in[5];
    const float* b1   = (const float*)d_in[6];
    const float* W2   = (const float*)d_in[7];
    const float* b2   = (const float*)d_in[8];
    const float* clfW = (const float*)d_in[9];
    const float* clfb = (const float*)d_in[10];
    float* out = (float*)d_out;

    const int N = in_sizes[0] / 64;   // 65536
    const int E = in_sizes[1] / 2;    // 1048576

    char* w = (char*)d_ws;
    size_t off = 0;
    auto take = [&](size_t bytes) -> void* {
        off = (off + 255) & ~(size_t)255;
        void* p = w + off;
        off += bytes;
        return p;
    };
    int*    deg      = (int*)take((size_t)N * 4);
    int*    rowptr   = (int*)take((size_t)(N + 1) * 4);
    int*    bcur     = (int*)take((size_t)NBKT * BSTRIDE * 4);
    int*    chunk    = (int*)take(256 * 4);
    float*  dinv     = (float*)take((size_t)N * 4);
    int*    csr      = (int*)take((size_t)E * 4);
    __half* y        = (__half*)take((size_t)N * 64 * 2);
    __half* hA       = (__half*)take((size_t)N * 64 * 2);
    __half* hB       = (__half*)take((size_t)N * 64 * 2);
    float*  partials = (float*)take((size_t)2048 * 128 * 4);
    float*  mean     = (float*)take(256);
    float*  rstd     = (float*)take(256);
    float*  Wf       = (float*)take(4096 * 4);
    float*  brow     = (float*)take(256);
    float*  psum     = (float*)take(64 * 64 * 4);
    float*  pcnt     = (float*)take(64 * 4);
    // buck (NBKT*CAP ints = 8MB) overlaid on hB (8MB fp16): buck dead after k_place,
    // hB first written in layer-1 k_agg.
    int* buck = (int*)hB;

    hipMemsetAsync(psum, 0, 64 * 64 * 4, stream);
    hipMemsetAsync(pcnt, 0, 64 * 4, stream);

    k_binit<<<(NBKT + 255) / 256, 256, 0, stream>>>(bcur);
    k_bin<<<E / 4096, 256, 0, stream>>>(ei, E, bcur, buck);
    k_cnt<<<NBKT, 256, 0, stream>>>(bcur, buck, deg);
    k_scan1<<<N / 256, 256, 0, stream>>>(deg, rowptr, chunk);
    k_scan2<<<1, 256, 0, stream>>>(chunk);
    k_scan3<<<N / 256, 256, 0, stream>>>(rowptr, chunk, deg, dinv, N, E);
    k_place<<<NBKT, 256, 0, stream>>>(bcur, buck, rowptr, csr);

    const float invN = 1.0f / (float)N;

    // layer 0 (input x fp32, no BN on input)
    k_fold<<<1, 256, 0, stream>>>(W0, mean, rstd, 0, Wf, brow);
    k_gemm<0><<<N / 64, 256, 0, stream>>>(x, Wf, brow, dinv, y);
    k_agg<1><<<2048, 512, 0, stream>>>(y, rowptr, csr, dinv, b0, hA, partials, N);
    k_stats<<<64, 256, 0, stream>>>(partials, 2048, mean, rstd, invN);

    // layer 1
    k_fold<<<1, 256, 0, stream>>>(W1, mean, rstd, 1, Wf, brow);
    k_gemm<1><<<N / 64, 256, 0, stream>>>(hA, Wf, brow, dinv, y);
    k_agg<1><<<2048, 512, 0, stream>>>(y, rowptr, csr, dinv, b1, hB, partials, N);
    k_stats<<<64, 256, 0, stream>>>(partials, 2048, mean, rstd, invN);

    // layer 2 (no relu)
    k_fold<<<1, 256, 0, stream>>>(W2, mean, rstd, 1, Wf, brow);
    k_gemm<1><<<N / 64, 256, 0, stream>>>(hB, Wf, brow, dinv, y);
    k_agg<0><<<2048, 512, 0, stream>>>(y, rowptr, csr, dinv, b2, hA, partials, N);
    k_stats<<<64, 256, 0, stream>>>(partials, 2048, mean, rstd, invN);

    // pool (applies final BN on the fly) + head
    k_pool<<<N / 64, 64, 0, stream>>>(hA, bat, mean, rstd, psum, pcnt);
    k_head<<<1, 1024, 0, stream>>>(psum, pcnt, clfW, clfb, out);
}

// Round 6
// 255.898 us; speedup vs baseline: 2.0128x; 1.0311x over previous
//
#include <hip/hip_runtime.h>
#include <hip/hip_fp16.h>

// GCN: 3x (GEMM(+BN fold) -> CSR aggregate -> bias/relu -> BN-stats),
// then segment mean-pool + linear head + softmax.
// Sizes fixed: N=65536 nodes, E=1048576 edges, F=H=64, 64 graphs, 16 classes.
//
// CSR build: LDS-local binning (bin) -> 1-block bucket scan -> place (LDS count +
// local scan + in-window scatter). History: flat scatter 18x write amplification (r2);
// global-atomic buckets serialize on counter lines (r3); 3-pass build works (r4).
// r5: fp16 activations halve gather traffic. r6: quad-gather k_agg (16 lanes x 4
// features, 4 edges per wave-load) to cut per-edge instruction count ~2x.

#define NBKT 512      // bucket = dst >> 7 (128 nodes per bucket)
#define CAP  4096     // slots per bucket (avg fill 2048)
#define BSTRIDE 16    // bcur padded: one counter per 64B line

__device__ inline unsigned pack2h(float a, float b) {
    __half ha = __float2half_rn(a), hb = __float2half_rn(b);
    unsigned short ua = *(unsigned short*)&ha, ub = *(unsigned short*)&hb;
    return (unsigned)ua | ((unsigned)ub << 16);
}

__device__ inline float4 cvt4(uint2 u) {
    __half2 h0 = *(__half2*)&u.x, h1 = *(__half2*)&u.y;
    float2 f0 = __half22float2(h0), f1 = __half22float2(h1);
    return {f0.x, f0.y, f1.x, f1.y};
}

__global__ void k_binit(int* __restrict__ bcur) {
    int t = blockIdx.x * 256 + threadIdx.x;
    if (t < NBKT) bcur[t * BSTRIDE] = t * CAP;
}

// partition edges into NBKT dst-buckets; entries packed (src<<7)|(dst&127)
__global__ void k_bin(const int* __restrict__ ei, int E, int* __restrict__ bcur,
                      int* __restrict__ buck) {
    __shared__ int sd[4096];
    __shared__ unsigned short bk[4096];
    __shared__ int cnt[NBKT], off[NBKT];
    int t = threadIdx.x;
    int base = blockIdx.x * 4096;
    for (int i = t; i < NBKT; i += 256) cnt[i] = 0;
    __syncthreads();
#pragma unroll
    for (int k = 0; k < 16; ++k) {
        int i = k * 256 + t;
        int e = base + i;
        int s = ei[e], d = ei[E + e];
        sd[i] = (s << 7) | (d & 127);
        int b = d >> 7;
        bk[i] = (unsigned short)b;
        atomicAdd(&cnt[b], 1);
    }
    __syncthreads();
    for (int b = t; b < NBKT; b += 256) {
        int c = cnt[b];
        off[b] = c ? atomicAdd(&bcur[b * BSTRIDE], c) : 0;
    }
    __syncthreads();
#pragma unroll
    for (int k = 0; k < 16; ++k) {
        int i = k * 256 + t;
        int b = bk[i];
        int p = atomicAdd(&off[b], 1);
        buck[p] = sd[i];
    }
}

// exclusive scan over bucket counts (bucket count = bcur_final - bucket_base_cap)
__global__ void k_scanB(const int* __restrict__ bcur, int* __restrict__ bbase,
                        int* __restrict__ rowptr, int N, int E) {
    __shared__ int s[NBKT];
    int t = threadIdx.x;
    int v = bcur[t * BSTRIDE] - t * CAP;
    s[t] = v;
    __syncthreads();
    for (int o = 1; o < NBKT; o <<= 1) {
        int x = (t >= o) ? s[t - o] : 0;
        __syncthreads();
        s[t] += x;
        __syncthreads();
    }
    bbase[t] = s[t] - v;
    if (t == 0) rowptr[N] = E;
}

// per bucket: count node degrees in LDS, local 128-scan -> rowptr/dinv, scatter csr
__global__ void k_place(const int* __restrict__ bcur, const int* __restrict__ buck,
                        const int* __restrict__ bbase, int* __restrict__ rowptr,
                        float* __restrict__ dinv, int* __restrict__ csr) {
    __shared__ int dc[128], sc[128], cur[128];
    int b = blockIdx.x, t = threadIdx.x;
    if (t < 128) dc[t] = 0;
    __syncthreads();
    int beg = b * CAP, end = bcur[b * BSTRIDE];
    for (int i = beg + t; i < end; i += 256) atomicAdd(&dc[buck[i] & 127], 1);
    __syncthreads();
    int v = (t < 128) ? dc[t] : 0;
    if (t < 128) sc[t] = v;
    __syncthreads();
    for (int o = 1; o < 128; o <<= 1) {
        int x = 0;
        if (t < 128 && t >= o) x = sc[t - o];
        __syncthreads();
        if (t < 128) sc[t] += x;
        __syncthreads();
    }
    if (t < 128) {
        int r = bbase[b] + sc[t] - v;   // exclusive
        rowptr[b * 128 + t] = r;
        cur[t] = r;
        dinv[b * 128 + t] = rsqrtf((float)(v + 1));  // +1 self loop
    }
    __syncthreads();
    for (int i = beg + t; i < end; i += 256) {
        int e = buck[i];
        int p = atomicAdd(&cur[e & 127], 1);
        csr[p] = e >> 7;
    }
}

// y[n][j] = fp16( dinv[n] * ( sum_f hnorm[n][f]*W[f][j] + brow[j] ) )
// BN fold done in-block: Ws = rstd[f]*W, brow[j] = -sum_f mean[f]*Ws[f][j].
// block 256 threads, 64 rows/block; thread = 4x4 output tile.
template <int HIN>
__global__ void k_gemm(const void* __restrict__ hv, const float* __restrict__ W,
                       const float* __restrict__ mean, const float* __restrict__ rstd,
                       int has_stats, const float* __restrict__ dinv,
                       __half* __restrict__ y) {
    __shared__ float Ws[4096];        // [f][c] 64x64, scaled by rstd[f]
    __shared__ float hs[64 * 65];     // [row][f], stride 65
    __shared__ float sm[64], sr[64], bs[64];
    int t = threadIdx.x;
    int rowBase = blockIdx.x * 64;
    if (t < 64) {
        sm[t] = has_stats ? mean[t] : 0.0f;
        sr[t] = has_stats ? rstd[t] : 1.0f;
    }
    __syncthreads();
#pragma unroll
    for (int k = 0; k < 4; ++k) {
        int i = t + k * 256;              // float4 index; row f = i>>4
        float4 wv = ((const float4*)W)[i];
        float s = sr[i >> 4];
        wv.x *= s; wv.y *= s; wv.z *= s; wv.w *= s;
        ((float4*)Ws)[i] = wv;
    }
    if (HIN) {
        const uint4* src = (const uint4*)((const __half*)hv + (size_t)rowBase * 64);
#pragma unroll
        for (int k = 0; k < 2; ++k) {
            int i = t + k * 256;          // 0..511 uint4s; each = 8 halves
            int row = i >> 3, c8 = i & 7;
            uint4 u = src[i];
            const __half2* hp = (const __half2*)&u;
            float* dst = &hs[row * 65 + c8 * 8];
#pragma unroll
            for (int j = 0; j < 4; ++j) {
                dst[2 * j + 0] = __low2float(hp[j]);
                dst[2 * j + 1] = __high2float(hp[j]);
            }
        }
    } else {
        const float4* src = (const float4*)((const float*)hv + (size_t)rowBase * 64);
#pragma unroll
        for (int k = 0; k < 4; ++k) {
            int i = t + k * 256;
            int row = i >> 4, c4 = i & 15;
            float4 v = src[i];
            float* dst = &hs[row * 65 + c4 * 4];
            dst[0] = v.x; dst[1] = v.y; dst[2] = v.z; dst[3] = v.w;
        }
    }
    __syncthreads();
    if (t < 64) {
        float acc = 0.0f;
        for (int f = 0; f < 64; ++f) acc += sm[f] * Ws[f * 64 + t];
        bs[t] = -acc;
    }
    __syncthreads();
    int rg = t >> 4;   // 0..15
    int cg = t & 15;   // 0..15
    float4 a0, a1, a2, a3;
    {
        float bx = bs[cg * 4 + 0], by = bs[cg * 4 + 1];
        float bz = bs[cg * 4 + 2], bw = bs[cg * 4 + 3];
        a0 = {bx, by, bz, bw}; a1 = a0; a2 = a0; a3 = a0;
    }
    const float* h0 = &hs[(rg * 4 + 0) * 65];
    const float* h1 = &hs[(rg * 4 + 1) * 65];
    const float* h2 = &hs[(rg * 4 + 2) * 65];
    const float* h3 = &hs[(rg * 4 + 3) * 65];
#pragma unroll 4
    for (int f = 0; f < 64; ++f) {
        float4 wv = ((float4*)Ws)[f * 16 + cg];
        float v0 = h0[f], v1 = h1[f], v2 = h2[f], v3 = h3[f];
        a0.x += v0 * wv.x; a0.y += v0 * wv.y; a0.z += v0 * wv.z; a0.w += v0 * wv.w;
        a1.x += v1 * wv.x; a1.y += v1 * wv.y; a1.z += v1 * wv.z; a1.w += v1 * wv.w;
        a2.x += v2 * wv.x; a2.y += v2 * wv.y; a2.z += v2 * wv.z; a2.w += v2 * wv.w;
        a3.x += v3 * wv.x; a3.y += v3 * wv.y; a3.z += v3 * wv.z; a3.w += v3 * wv.w;
    }
    float d0 = dinv[rowBase + rg * 4 + 0];
    float d1 = dinv[rowBase + rg * 4 + 1];
    float d2 = dinv[rowBase + rg * 4 + 2];
    float d3 = dinv[rowBase + rg * 4 + 3];
    uint2* y2 = (uint2*)y;
    size_t ob = (size_t)(rowBase + rg * 4) * 16 + cg;
    y2[ob + 0]  = {pack2h(a0.x * d0, a0.y * d0), pack2h(a0.z * d0, a0.w * d0)};
    y2[ob + 16] = {pack2h(a1.x * d1, a1.y * d1), pack2h(a1.z * d1, a1.w * d1)};
    y2[ob + 32] = {pack2h(a2.x * d2, a2.y * d2), pack2h(a2.z * d2, a2.w * d2)};
    y2[ob + 48] = {pack2h(a3.x * d3, a3.y * d3), pack2h(a3.z * d3, a3.w * d3)};
}

// out[n] = relu?( dinv[n]*(y[n] + sum_{src} y[src]) + bias ), stored fp16.
// Quad-gather: quarter q (16 lanes) holds 4 features (uint2) and processes edges
// beg+q, beg+4+q, ...; main loop unmasked, tail masked, self-term after combine.
template <int RELU>
__global__ void k_agg(const __half* __restrict__ y, const int* __restrict__ rowptr,
                      const int* __restrict__ csr, const float* __restrict__ dinv,
                      const float* __restrict__ bias, __half* __restrict__ hout,
                      float* __restrict__ partials, int N) {
    int t = threadIdx.x;
    int lane = t & 63;
    int wid = t >> 6;                       // 0..7
    int q = lane >> 4;                      // quarter 0..3
    int l = lane & 15;                      // features 4l..4l+3
    int gwave = blockIdx.x * 8 + wid;       // 0..16383
    float4 bv = ((const float4*)bias)[l];
    float4 ps = {0, 0, 0, 0}, pq = {0, 0, 0, 0};
    const uint2* y2 = (const uint2*)y;      // row = 16 uint2
    for (int n = gwave; n < N; n += 16384) {
        int beg = rowptr[n], end = rowptr[n + 1];
        int d = end - beg;
        const int* cp = csr + beg;
        float4 acc = {0, 0, 0, 0};
        int nfull = d >> 2;
        int i = 0;
        for (; i + 4 <= nfull; i += 4) {    // 16 edges per iter, 4 chains in flight
            int s0 = cp[4 * i + q];
            int s1 = cp[4 * i + 4 + q];
            int s2 = cp[4 * i + 8 + q];
            int s3 = cp[4 * i + 12 + q];
            uint2 u0 = y2[(size_t)s0 * 16 + l];
            uint2 u1 = y2[(size_t)s1 * 16 + l];
            uint2 u2 = y2[(size_t)s2 * 16 + l];
            uint2 u3 = y2[(size_t)s3 * 16 + l];
            float4 v0 = cvt4(u0), v1 = cvt4(u1), v2 = cvt4(u2), v3 = cvt4(u3);
            acc.x += v0.x + v1.x + v2.x + v3.x;
            acc.y += v0.y + v1.y + v2.y + v3.y;
            acc.z += v0.z + v1.z + v2.z + v3.z;
            acc.w += v0.w + v1.w + v2.w + v3.w;
        }
        for (; i < nfull; ++i) {
            int s0 = cp[4 * i + q];
            uint2 u0 = y2[(size_t)s0 * 16 + l];
            float4 v0 = cvt4(u0);
            acc.x += v0.x; acc.y += v0.y; acc.z += v0.z; acc.w += v0.w;
        }
        int r = d & 3;
        if (r) {
            int e = min(4 * nfull + q, d - 1);
            uint2 u0 = y2[(size_t)cp[e] * 16 + l];
            float4 v0 = cvt4(u0);
            if (q < r) {
                acc.x += v0.x; acc.y += v0.y; acc.z += v0.z; acc.w += v0.w;
            }
        }
        // combine quarters
#pragma unroll
        for (int o = 16; o <= 32; o <<= 1) {
            acc.x += __shfl_xor(acc.x, o);
            acc.y += __shfl_xor(acc.y, o);
            acc.z += __shfl_xor(acc.z, o);
            acc.w += __shfl_xor(acc.w, o);
        }
        float4 vs = cvt4(y2[(size_t)n * 16 + l]);   // self term
        float dv = dinv[n];
        float4 val;
        val.x = (acc.x + vs.x) * dv + bv.x;
        val.y = (acc.y + vs.y) * dv + bv.y;
        val.z = (acc.z + vs.z) * dv + bv.z;
        val.w = (acc.w + vs.w) * dv + bv.w;
        if (RELU) {
            val.x = fmaxf(val.x, 0.0f); val.y = fmaxf(val.y, 0.0f);
            val.z = fmaxf(val.z, 0.0f); val.w = fmaxf(val.w, 0.0f);
        }
        if (q == 0) {
            uint2 o2;
            o2.x = pack2h(val.x, val.y);
            o2.y = pack2h(val.z, val.w);
            ((uint2*)hout)[(size_t)n * 16 + l] = o2;
        }
        ps.x += val.x; ps.y += val.y; ps.z += val.z; ps.w += val.w;
        pq.x += val.x * val.x; pq.y += val.y * val.y;
        pq.z += val.z * val.z; pq.w += val.w * val.w;
    }
    __shared__ float S[8][64], Q[8][64];
    if (q == 0) {
        ((float4*)S[wid])[l] = ps;
        ((float4*)Q[wid])[l] = pq;
    }
    __syncthreads();
    if (t < 64) {
        float s = 0.0f, qq = 0.0f;
#pragma unroll
        for (int w = 0; w < 8; ++w) {
            s += S[w][t];
            qq += Q[w][t];
        }
        partials[(size_t)blockIdx.x * 128 + t] = s;
        partials[(size_t)blockIdx.x * 128 + 64 + t] = qq;
    }
}

// one block per feature: reduce partials -> mean, rstd
__global__ void k_stats(const float* __restrict__ partials, int nblk,
                        float* __restrict__ mean, float* __restrict__ rstd, float invN) {
    __shared__ float sh[256];
    int f = blockIdx.x, t = threadIdx.x;
    float s = 0.0f, q = 0.0f;
    for (int b = t; b < nblk; b += 256) {
        s += partials[(size_t)b * 128 + f];
        q += partials[(size_t)b * 128 + 64 + f];
    }
    sh[t] = s;
    __syncthreads();
    for (int o = 128; o > 0; o >>= 1) {
        if (t < o) sh[t] += sh[t + o];
        __syncthreads();
    }
    float S = sh[0];
    __syncthreads();
    sh[t] = q;
    __syncthreads();
    for (int o = 128; o > 0; o >>= 1) {
        if (t < o) sh[t] += sh[t + o];
        __syncthreads();
    }
    if (t == 0) {
        float Qs = sh[0];
        float m = S * invN;
        float var = Qs * invN - m * m;
        mean[f] = m;
        rstd[f] = rsqrtf(var + 1e-5f);
    }
}

// mean pool with on-the-fly BN of final layer; batch is sorted -> per-run register accum
__global__ void k_pool(const __half* __restrict__ h, const int* __restrict__ batch,
                       const float* __restrict__ mean, const float* __restrict__ rstd,
                       float* __restrict__ psum, float* __restrict__ pcnt) {
    int lane = threadIdx.x;
    int base = blockIdx.x * 64;
    float m = mean[lane], r = rstd[lane];
    int cur = batch[base];
    float acc = 0.0f;
    int runlen = 0;
    for (int i = 0; i < 64; ++i) {
        int n = base + i;
        int g = batch[n];
        if (g != cur) {
            atomicAdd(&psum[cur * 64 + lane], acc);
            if (lane == 0) atomicAdd(&pcnt[cur], (float)runlen);
            acc = 0.0f;
            runlen = 0;
            cur = g;
        }
        acc += (__half2float(h[(size_t)n * 64 + lane]) - m) * r;
        runlen++;
    }
    atomicAdd(&psum[cur * 64 + lane], acc);
    if (lane == 0) atomicAdd(&pcnt[cur], (float)runlen);
}

// logits = pooled @ clfW^T + clfb ; softmax over 16 classes. 1 block x 1024 threads.
__global__ void k_head(const float* __restrict__ psum, const float* __restrict__ pcnt,
                       const float* __restrict__ clfW, const float* __restrict__ clfb,
                       float* __restrict__ out) {
    __shared__ float ps[64 * 64];
    __shared__ float wl[16 * 64];
    __shared__ float ci[64];
    int t = threadIdx.x;
    ((float4*)ps)[t] = ((const float4*)psum)[t];
    if (t < 256) ((float4*)wl)[t] = ((const float4*)clfW)[t];
    if (t < 64) ci[t] = 1.0f / fmaxf(pcnt[t], 1.0f);
    __syncthreads();
    int g = t >> 4, c = t & 15;
    float acc = 0.0f;
#pragma unroll 8
    for (int f = 0; f < 64; ++f) acc += ps[g * 64 + f] * wl[c * 64 + f];
    acc = acc * ci[g] + clfb[c];
    float mx = acc;
    for (int o = 1; o < 16; o <<= 1) mx = fmaxf(mx, __shfl_xor(mx, o, 16));
    float e = __expf(acc - mx);
    float s = e;
    for (int o = 1; o < 16; o <<= 1) s += __shfl_xor(s, o, 16);
    out[t] = e / s;
}

extern "C" void kernel_launch(void* const* d_in, const int* in_sizes, int n_in,
                              void* d_out, int out_size, void* d_ws, size_t ws_size,
                              hipStream_t stream) {
    const float* x    = (const float*)d_in[0];
    const int*   ei   = (const int*)d_in[1];
    const int*   bat  = (const int*)d_in[2];
    const float* W0   = (const float*)d_in[3];
    const float* b0   = (const float*)d_in[4];
    const float* W1   = (const float*)d_in[5];
    const float* b1   = (const float*)d_in[6];
    const float* W2   = (const float*)d_in[7];
    const float* b2   = (const float*)d_in[8];
    const float* clfW = (const float*)d_in[9];
    const float* clfb = (const float*)d_in[10];
    float* out = (float*)d_out;

    const int N = in_sizes[0] / 64;   // 65536
    const int E = in_sizes[1] / 2;    // 1048576

    char* w = (char*)d_ws;
    size_t off = 0;
    auto take = [&](size_t bytes) -> void* {
        off = (off + 255) & ~(size_t)255;
        void* p = w + off;
        off += bytes;
        return p;
    };
    int*    rowptr   = (int*)take((size_t)(N + 1) * 4);
    int*    bcur     = (int*)take((size_t)NBKT * BSTRIDE * 4);
    int*    bbase    = (int*)take((size_t)NBKT * 4);
    float*  dinv     = (float*)take((size_t)N * 4);
    int*    csr      = (int*)take((size_t)E * 4);
    __half* y        = (__half*)take((size_t)N * 64 * 2);
    __half* hA       = (__half*)take((size_t)N * 64 * 2);
    __half* hB       = (__half*)take((size_t)N * 64 * 2);
    float*  partials = (float*)take((size_t)2048 * 128 * 4);
    float*  mean     = (float*)take(256);
    float*  rstd     = (float*)take(256);
    float*  psum     = (float*)take(64 * 64 * 4);
    float*  pcnt     = (float*)take(64 * 4);
    // buck (NBKT*CAP ints = 8MB) overlaid on hB (8MB fp16): buck dead after k_place,
    // hB first written in layer-1 k_agg.
    int* buck = (int*)hB;

    hipMemsetAsync(psum, 0, 64 * 64 * 4, stream);
    hipMemsetAsync(pcnt, 0, 64 * 4, stream);

    k_binit<<<(NBKT + 255) / 256, 256, 0, stream>>>(bcur);
    k_bin<<<E / 4096, 256, 0, stream>>>(ei, E, bcur, buck);
    k_scanB<<<1, NBKT, 0, stream>>>(bcur, bbase, rowptr, N, E);
    k_place<<<NBKT, 256, 0, stream>>>(bcur, buck, bbase, rowptr, dinv, csr);

    const float invN = 1.0f / (float)N;

    // layer 0 (input x fp32, no BN on input)
    k_gemm<0><<<N / 64, 256, 0, stream>>>(x, W0, mean, rstd, 0, dinv, y);
    k_agg<1><<<2048, 512, 0, stream>>>(y, rowptr, csr, dinv, b0, hA, partials, N);
    k_stats<<<64, 256, 0, stream>>>(partials, 2048, mean, rstd, invN);

    // layer 1
    k_gemm<1><<<N / 64, 256, 0, stream>>>(hA, W1, mean, rstd, 1, dinv, y);
    k_agg<1><<<2048, 512, 0, stream>>>(y, rowptr, csr, dinv, b1, hB, partials, N);
    k_stats<<<64, 256, 0, stream>>>(partials, 2048, mean, rstd, invN);

    // layer 2 (no relu)
    k_gemm<1><<<N / 64, 256, 0, stream>>>(hB, W2, mean, rstd, 1, dinv, y);
    k_agg<0><<<2048, 512, 0, stream>>>(y, rowptr, csr, dinv, b2, hA, partials, N);
    k_stats<<<64, 256, 0, stream>>>(partials, 2048, mean, rstd, invN);

    // pool (applies final BN on the fly) + head
    k_pool<<<N / 64, 64, 0, stream>>>(hA, bat, mean, rstd, psum, pcnt);
    k_head<<<1, 1024, 0, stream>>>(psum, pcnt, clfW, clfb, out);
}